// Round 14
// baseline (269.106 us; speedup 1.0000x reference)
//
#include <hip/hip_runtime.h>
#include <hip/hip_bf16.h>
#include <math.h>

typedef __attribute__((ext_vector_type(4))) float f32x4;
typedef __attribute__((ext_vector_type(8))) int i32x8;
typedef __attribute__((ext_vector_type(4))) int i32x4;

#define BM 128
#define BN 128
#define BK 128
#define TEMP_INV 14.2857142857142857f   // 1/0.07
#define UNIT_SCALE 0x7f7f7f7f           // E8M0 127 -> x1.0 exact (verified)

union frag32 {
  i32x8 v8;
  struct { i32x4 lo; i32x4 hi; } s;
};

// ---- async global->LDS, 16B per lane
static __device__ inline void async16(const void* g, void* l) {
  __builtin_amdgcn_global_load_lds(
      (const __attribute__((address_space(1))) unsigned int*)g,
      (__attribute__((address_space(3))) unsigned int*)l,
      16, 0, 0);
}

// ============================================================
// A layout (pre-tiled fragments, K=128 version of R8's verified map):
//   tile (rt, kg) = rows [rt*16,+16) x K-bytes [kg*128,+128), stored as
//   2 KB at (rt*8 + kg)*2048. Lane slot s = q*16 + r15 (q = K-quarter)
//   holds the 32 contiguous bytes [q*32,+32) of row r15 -> exactly the
//   A-fragment of mfma 16x16x128 (lane l: row l&15, q = l>>4).
//   A wave loads its tile with two dwordx4 at lane*32 and lane*32+16.
// B layout: plain row-major (LDS staging path).
// ============================================================

// ============================================================
// Kernel 1: L2-normalize rows of A and B (D=1024), emit fp8 e4m3.
// A -> tiled fragment layout; B -> row-major. Zeroes pos/neg.
// ============================================================
__global__ __launch_bounds__(256) void normalize_rows(
    const float* __restrict__ a, const float* __restrict__ b,
    unsigned char* __restrict__ oa, unsigned char* __restrict__ ob,
    float* __restrict__ pos_acc, float* __restrict__ neg_acc,
    int N, int D) {
  const int blk = blockIdx.x;
  const bool isA = blk < N;
  const int row = isA ? blk : blk - N;
  const float* in = (isA ? a : b) + (size_t)row * D;
  if (isA && threadIdx.x == 0) { pos_acc[row] = 0.f; neg_acc[row] = 0.f; }

  const int t = threadIdx.x;
  const float4 v = ((const float4*)in)[t];
  float ss = v.x * v.x + v.y * v.y + v.z * v.z + v.w * v.w;
#pragma unroll
  for (int m = 32; m >= 1; m >>= 1) ss += __shfl_xor(ss, m, 64);
  __shared__ float wsum[4];
  const int wave = t >> 6, lane = t & 63;
  if (lane == 0) wsum[wave] = ss;
  __syncthreads();
  const float tot = wsum[0] + wsum[1] + wsum[2] + wsum[3];
  const float inv = 1.0f / fmaxf(sqrtf(tot), 1e-12f);
  int r = __builtin_amdgcn_cvt_pk_fp8_f32(v.x * inv, v.y * inv, 0, false);
  r = __builtin_amdgcn_cvt_pk_fp8_f32(v.z * inv, v.w * inv, r, true);
  if (isA) {
    // thread t owns K-bytes [4t, 4t+4): kg = t>>5, dword-in-group d = t&31,
    // q = d>>3, slot s = q*16 + (row&15), dword-in-slot = d&7
    const int rt = row >> 4, r15 = row & 15;
    const int kg = t >> 5, d = t & 31;
    const int s = (d >> 3) * 16 + r15;
    const size_t outIdx = ((size_t)(rt * 8 + kg) << 9) + s * 8 + (d & 7);
    ((int*)oa)[outIdx] = r;
  } else {
    ((int*)(ob + (size_t)row * D))[t] = r;
  }
}

// ============================================================
// Kernel 2: fused MX-fp8 MFMA GEMM (A[N,D] x B[M,D]^T) + exp epilogue.
// R10 skeleton (mfma_scale_f32_16x16x128_f8f6f4, BK=128, 2-barrier
// phases) with HYBRID transport:
//   - B: global_load_lds -> swizzled 16 KB LDS -> ds_read_b128 (R10 path)
//   - A: DIRECT global->VGPR from pre-tiled fragments (2 dwordx4/tile),
//     L1/L2-cached (wn-pair waves share A tiles).
// LDS pipe demand per block-phase drops ~1150 -> ~576 cyc (reads 64->32
// b128, staging DMA 32->16 KB) -- it was the saturated pipe in R10/R13.
// LDS 16 KB/block. C/D layout (16x16, verified): col=lane&15,
// row=(lane>>4)*4+reg.
// ============================================================
__global__ __launch_bounds__(256, 3) void infonce_gemm(
    const unsigned char* __restrict__ A, const unsigned char* __restrict__ B,
    const int* __restrict__ la, const int* __restrict__ lb,
    float* __restrict__ pos_acc, float* __restrict__ neg_acc, int D) {
  __shared__ __align__(16) unsigned char sB[BN * BK];  // 16 KB

  const int tid = threadIdx.x;
  const int lane = tid & 63;
  const int wave = tid >> 6;
  const int wm = wave >> 1;  // 0..1
  const int wn = wave & 1;   // 0..1
  const int row0 = blockIdx.y * BM;
  const int col0 = blockIdx.x * BN;

  // B staging: call c covers rows c*32 + (tid>>3); within-row logical
  // 16B slot l = (tid&7) ^ ((tid>>3)&7)  (swizzle: slot s of row r at s^(r&7))
  const int srow = tid >> 3;
  const int sl = ((tid & 7) ^ (srow & 7)) * 16;
  const unsigned char* gB = B + (size_t)(col0 + srow) * D + sl;

  // A direct: tile rt = blockIdx.y*8 + wm*4 + i, base (rt*8 + kg)*2048
  const unsigned char* pa[4];
#pragma unroll
  for (int i = 0; i < 4; i++)
    pa[i] = A + ((size_t)(blockIdx.y * 8 + wm * 4 + i) * 8) * 2048 + lane * 32;

  f32x4 acc[4][4] = {};

  const int q = lane >> 4;    // 0..3
  const int l15 = lane & 15;  // 0..15
  const int phys0 = ((2 * q) ^ (l15 & 7)) * 16;  // loop-invariant

#define STAGE_B(kk)                                                 \
  do {                                                              \
    _Pragma("unroll") for (int c = 0; c < 4; c++) {                 \
      async16(gB + (size_t)c * 32 * 1024 + (kk),                    \
              &sB[(c * 256 + tid) * 16]);                           \
    }                                                               \
  } while (0)

  // lane's 32B B-fragment for tile-row rr from swizzled LDS
#define LOADB(dst, rr)                                          \
  do {                                                          \
    const unsigned char* _p = &sB[(rr) * BK];                   \
    frag32 _f;                                                  \
    _f.s.lo = *(const i32x4*)(_p + phys0);                      \
    _f.s.hi = *(const i32x4*)(_p + (phys0 ^ 16));               \
    dst = _f.v8;                                                \
  } while (0)

  // lane's 32B A-fragment: direct global from pre-tiled layout
#define LOADA(dst, i, kgoff)                                    \
  do {                                                          \
    frag32 _f;                                                  \
    _f.s.lo = *(const i32x4*)(pa[i] + (kgoff));                 \
    _f.s.hi = *(const i32x4*)(pa[i] + (kgoff) + 16);            \
    dst = _f.v8;                                                \
  } while (0)

#pragma unroll 1
  for (int k0 = 0; k0 < D; k0 += BK) {
    STAGE_B(k0);
    const int kgoff = (k0 >> 7) * 2048;
    __syncthreads();  // drain B staging; tile visible
    i32x8 bf0, bf1, bf2, bf3;
    LOADB(bf0, wn * 64 + 0 + l15);
    LOADB(bf1, wn * 64 + 16 + l15);
    LOADB(bf2, wn * 64 + 32 + l15);
    LOADB(bf3, wn * 64 + 48 + l15);
#pragma unroll
    for (int i = 0; i < 4; i++) {
      i32x8 af;
      LOADA(af, i, kgoff);
      acc[i][0] = __builtin_amdgcn_mfma_scale_f32_16x16x128_f8f6f4(
          af, bf0, acc[i][0], 0, 0, 0, UNIT_SCALE, 0, UNIT_SCALE);
      acc[i][1] = __builtin_amdgcn_mfma_scale_f32_16x16x128_f8f6f4(
          af, bf1, acc[i][1], 0, 0, 0, UNIT_SCALE, 0, UNIT_SCALE);
      acc[i][2] = __builtin_amdgcn_mfma_scale_f32_16x16x128_f8f6f4(
          af, bf2, acc[i][2], 0, 0, 0, UNIT_SCALE, 0, UNIT_SCALE);
      acc[i][3] = __builtin_amdgcn_mfma_scale_f32_16x16x128_f8f6f4(
          af, bf3, acc[i][3], 0, 0, 0, UNIT_SCALE, 0, UNIT_SCALE);
    }
    __syncthreads();  // all B reads done before next STAGE overwrites
  }

  // ---- epilogue: C/D layout col = lane&15, row = quad*4 + reg (verified)
  int lbv[4];
#pragma unroll
  for (int j = 0; j < 4; j++) lbv[j] = lb[col0 + wn * 64 + j * 16 + l15];

#pragma unroll
  for (int i = 0; i < 4; i++) {
#pragma unroll
    for (int r = 0; r < 4; r++) {
      const int row = row0 + wm * 64 + i * 16 + q * 4 + r;
      const int lav = la[row];
      float sneg = 0.f, spos = 0.f;
#pragma unroll
      for (int j = 0; j < 4; j++) {
        float s = acc[i][j][r] * TEMP_INV;
        s = fminf(fmaxf(s, -50.f), 50.f);
        const float e = __expf(s);
        sneg += e;
        if (lav == lbv[j]) spos += e;
      }
#pragma unroll
      for (int m = 8; m >= 1; m >>= 1) {
        sneg += __shfl_xor(sneg, m, 16);
        spos += __shfl_xor(spos, m, 16);
      }
      if (l15 == 0) {
        atomicAdd(&neg_acc[row], sneg);
        atomicAdd(&pos_acc[row], spos);
      }
    }
  }
}

// ============================================================
// Kernel 3: loss = mean( log(neg) - log(max(pos,1e-8)) )
// ============================================================
__global__ __launch_bounds__(1024) void final_reduce(
    const float* __restrict__ pos, const float* __restrict__ neg,
    float* __restrict__ out, int N) {
  double local = 0.0;
  const int t = threadIdx.x;
  for (int i = t; i < N / 4; i += 1024) {
    const float4 p4 = ((const float4*)pos)[i];
    const float4 n4 = ((const float4*)neg)[i];
    local += (double)(logf(n4.x) - logf(fmaxf(p4.x, 1e-8f)));
    local += (double)(logf(n4.y) - logf(fmaxf(p4.y, 1e-8f)));
    local += (double)(logf(n4.z) - logf(fmaxf(p4.z, 1e-8f)));
    local += (double)(logf(n4.w) - logf(fmaxf(p4.w, 1e-8f)));
  }
#pragma unroll
  for (int m = 32; m >= 1; m >>= 1) local += __shfl_xor(local, m, 64);
  __shared__ double wsum[16];
  const int wave = t >> 6, lane = t & 63;
  if (lane == 0) wsum[wave] = local;
  __syncthreads();
  if (t == 0) {
    double tot = 0.0;
#pragma unroll
    for (int w = 0; w < 16; w++) tot += wsum[w];
    out[0] = (float)(tot / (double)N);
  }
}

extern "C" void kernel_launch(void* const* d_in, const int* in_sizes, int n_in,
                              void* d_out, int out_size, void* d_ws, size_t ws_size,
                              hipStream_t stream) {
  const float* fa = (const float*)d_in[0];
  const float* fb = (const float*)d_in[1];
  const int* la = (const int*)d_in[2];
  const int* lb = (const int*)d_in[3];

  const int D = 1024;
  const int N = in_sizes[0] / D;  // 8192
  const int M = in_sizes[1] / D;  // 8192

  unsigned char* nA = (unsigned char*)d_ws;
  unsigned char* nB = nA + (size_t)N * D;
  float* pos = (float*)(nB + (size_t)M * D);
  float* neg = pos + N;

  normalize_rows<<<N + M, 256, 0, stream>>>(fa, fb, nA, nB, pos, neg, N, D);

  dim3 grid(M / BN, N / BM);
  infonce_gemm<<<grid, 256, 0, stream>>>(nA, nB, la, lb, pos, neg, D);

  final_reduce<<<1, 1024, 0, stream>>>(pos, neg, (float*)d_out, N);
}